// Round 1
// baseline (586.736 us; speedup 1.0000x reference)
//
#include <hip/hip_runtime.h>
#include <hip/hip_bf16.h>
#include <math.h>

typedef __attribute__((ext_vector_type(8))) short bf16x8;
typedef __attribute__((ext_vector_type(4))) float f32x4;
typedef __attribute__((ext_vector_type(8))) unsigned short u16x8;

#define MFMA16(a, b, c) __builtin_amdgcn_mfma_f32_16x16x32_bf16(a, b, c, 0, 0, 0)
#define LOG2E 1.4426950408889634f

__device__ __forceinline__ unsigned short f2b(float f) {
  __hip_bfloat16 h = __float2bfloat16(f);
  return *reinterpret_cast<unsigned short*>(&h);
}

__device__ __forceinline__ unsigned int pk2(float lo, float hi) {
  return (unsigned int)f2b(lo) | ((unsigned int)f2b(hi) << 16);
}

// load 8 fp32, return 8 bf16 packed in a uint4
__device__ __forceinline__ uint4 cvt8(const float* __restrict__ p) {
  float4 a = *(const float4*)p;
  float4 b = *(const float4*)(p + 4);
  union {
    unsigned short us[8];
    uint4 u;
  } r;
  r.us[0] = f2b(a.x); r.us[1] = f2b(a.y); r.us[2] = f2b(a.z); r.us[3] = f2b(a.w);
  r.us[4] = f2b(b.x); r.us[5] = f2b(b.y); r.us[6] = f2b(b.z); r.us[7] = f2b(b.w);
  return r.u;
}

// flat fp32 -> bf16 convert, 8 elems/thread
__global__ __launch_bounds__(256) void conv_f32_bf16(
    const float* __restrict__ in, unsigned short* __restrict__ out) {
  size_t i = ((size_t)blockIdx.x * 256 + threadIdx.x) * 8;
  *(uint4*)&out[i] = cvt8(in + i);
}

// out_bf16[c][r] = bf16(in_f32[r][c]); R, C multiples of 64
__global__ __launch_bounds__(256) void transpose_f32_bf16(
    const float* __restrict__ in, unsigned short* __restrict__ out, int R,
    int C) {
  __shared__ unsigned short tile[64][72];
  const int tR = blockIdx.y * 64, tC = blockIdx.x * 64;
  const int t = threadIdx.x;
#pragma unroll
  for (int p = 0; p < 4; ++p) {
    int u = t + p * 256, r = u >> 4, c = (u & 15) * 4;
    float4 v = *(const float4*)&in[(size_t)(tR + r) * C + tC + c];
    tile[r][c] = f2b(v.x);
    tile[r][c + 1] = f2b(v.y);
    tile[r][c + 2] = f2b(v.z);
    tile[r][c + 3] = f2b(v.w);
  }
  __syncthreads();
#pragma unroll
  for (int p = 0; p < 2; ++p) {
    int u = t + p * 256, orow = u >> 3, oc = (u & 7) * 8;
    u16x8 v;
#pragma unroll
    for (int e = 0; e < 8; ++e) v[e] = tile[oc + e][orow];
    *(u16x8*)&out[(size_t)(tC + orow) * R + tR + oc] = v;
  }
}

// C[M][N] = A[M][K] * Bt[N][K]^T, 128x128 tile, 4 waves, 16x16x32 MFMA.
// A is bf16. MODE 0: epilogue splits into Q*scale / K / V^T head layouts.
// MODE 1: epilogue adds fp32 bias, stores fp32 row-major.
template <int MODE>
__global__ __launch_bounds__(256, 2) void gemm_bt(
    const unsigned short* __restrict__ A, const unsigned short* __restrict__ Bt,
    unsigned short* __restrict__ O0, unsigned short* __restrict__ O1,
    unsigned short* __restrict__ O2, float* __restrict__ OF,
    const float* __restrict__ bias, int K, int N) {
  __shared__ unsigned short sA[128][40];
  __shared__ unsigned short sB[128][40];
  const int m0 = blockIdx.y * 128, n0 = blockIdx.x * 128;
  const int t = threadIdx.x;
  const int wave = t >> 6, lane = t & 63, quad = lane >> 4, t16 = lane & 15;
  const int wr = (wave >> 1) * 64, wc = (wave & 1) * 64;
  const int sr = t >> 2, sc = (t & 3) * 8;

  f32x4 acc[4][4];
#pragma unroll
  for (int i = 0; i < 4; ++i)
#pragma unroll
    for (int j = 0; j < 4; ++j) acc[i][j] = (f32x4){0.f, 0.f, 0.f, 0.f};

  const unsigned short* Ap = A + (size_t)(m0 + sr) * K + sc;
  const unsigned short* Bp = Bt + (size_t)(n0 + sr) * K + sc;
  const size_t rowK64 = (size_t)64 * K;

  for (int k0 = 0; k0 < K; k0 += 32) {
    uint4 a0 = *(const uint4*)(Ap + k0);
    uint4 a1 = *(const uint4*)(Ap + rowK64 + k0);
    uint4 b0 = *(const uint4*)(Bp + k0);
    uint4 b1 = *(const uint4*)(Bp + rowK64 + k0);
    __syncthreads();
    *(uint4*)&sA[sr][sc] = a0;
    *(uint4*)&sA[sr + 64][sc] = a1;
    *(uint4*)&sB[sr][sc] = b0;
    *(uint4*)&sB[sr + 64][sc] = b1;
    __syncthreads();
    bf16x8 af[4], bf[4];
#pragma unroll
    for (int i = 0; i < 4; ++i)
      af[i] = *(const bf16x8*)&sA[wr + i * 16 + t16][quad * 8];
#pragma unroll
    for (int j = 0; j < 4; ++j)
      bf[j] = *(const bf16x8*)&sB[wc + j * 16 + t16][quad * 8];
#pragma unroll
    for (int i = 0; i < 4; ++i)
#pragma unroll
      for (int j = 0; j < 4; ++j) acc[i][j] = MFMA16(af[i], bf[j], acc[i][j]);
  }

#pragma unroll
  for (int i = 0; i < 4; ++i) {
    const int mrow = m0 + wr + i * 16 + quad * 4;  // + r
#pragma unroll
    for (int j = 0; j < 4; ++j) {
      const int ncol = n0 + wc + j * 16 + t16;
#pragma unroll
      for (int r = 0; r < 4; ++r) {
        const float v = acc[i][j][r];
        const int mr = mrow + r;
        if (MODE == 0) {
          const int bb = mr >> 11, nn = mr & 2047;
          const int sec = ncol >> 10, rem = ncol & 1023;
          const int hh = rem >> 6, dd = rem & 63;
          const size_t bhh = (size_t)bb * 16 + hh;
          if (sec == 0)  // Q * (scale*log2e): softmax runs in log2 domain
            O0[(bhh * 2048 + nn) * 64 + dd] = f2b(v * (0.125f * LOG2E));
          else if (sec == 1)
            O1[(bhh * 2048 + nn) * 64 + dd] = f2b(v);  // K
          else
            O2[(bhh * 64 + dd) * 2048 + nn] = f2b(v);  // V^T
        } else {
          OF[(size_t)mr * N + ncol] = v + bias[ncol];
        }
      }
    }
  }
}

// Flash attention: block = (b,h, 64-row q tile), 4 waves of 16 q rows each.
// qt-major-descending dispatch order; K/V reg-prefetch pipeline; softmax in
// log2 domain. Swapped-operand QK^T (S^T = K*Q^T): each lane owns one full
// q-row of S (16 keys in-lane, x4 quad-siblings) so row max/sum are in-lane
// trees + 2 cross-quad shuffles instead of 16-lane shuffle reductions; bias
// loads become float4; causal mask only on the diagonal tile; P repacked to
// LDS via 4x ds_write_b64; accO rescale skipped when no row max grows.
__global__ __launch_bounds__(256, 4) void attn_kernel(
    const unsigned short* __restrict__ Q, const unsigned short* __restrict__ Kb,
    const unsigned short* __restrict__ Vt, const float* __restrict__ PB,
    unsigned short* __restrict__ Ao) {
  __shared__ unsigned short sK[64][72];
  __shared__ unsigned short sV[64][72];   // sV[d][key]
  __shared__ unsigned short sQP[64][72];  // Q staging, then per-wave P buffer

  const int bh = blockIdx.x & 63;
  const int qt = 31 - (blockIdx.x >> 6);  // heavy q-tiles dispatch first
  const int h = bh & 15;
  const int b = bh >> 4;
  const int q0 = qt * 64;
  const int t = threadIdx.x;
  const int wave = t >> 6, lane = t & 63, quad = lane >> 4, t16 = lane & 15;
  const int kloc = quad * 4;  // this lane's local key base within a 16-chunk

  const size_t qbase = ((size_t)bh * 2048 + q0) * 64;
#pragma unroll
  for (int p = 0; p < 2; ++p) {
    int u = t + p * 256, r = u >> 3, c = (u & 7) * 8;
    *(uint4*)&sQP[r][c] = *(const uint4*)&Q[qbase + r * 64 + c];
  }
  __syncthreads();
  const bf16x8 qa0 = *(const bf16x8*)&sQP[wave * 16 + t16][quad * 8];
  const bf16x8 qa1 = *(const bf16x8*)&sQP[wave * 16 + t16][32 + quad * 8];
  // sQP is reused as P buffer inside the loop; iteration-0's two barriers
  // order every wave's Q-frag reads before the first P write.

  f32x4 accO[4];
#pragma unroll
  for (int i = 0; i < 4; ++i) accO[i] = (f32x4){0.f, 0.f, 0.f, 0.f};
  float m = -INFINITY, l = 0.f;  // per-lane: stats for ONE q row

  const int qrow = q0 + wave * 16 + t16;  // this lane's q row
  const int r0 = t >> 3, c0 = (t & 7) * 8;
  const size_t kvrow = (size_t)bh * 2048 * 64;
  // bias for this lane's row: components r=0..3 are consecutive keys
  const float* pbp =
      PB + (size_t)h * 4194304 + (size_t)qrow * 2048 + kloc;

  // ---- prefetch tile 0 (K/V into regs, bias as float4) ----
  uint4 kv0 = *(const uint4*)&Kb[kvrow + (size_t)r0 * 64 + c0];
  uint4 kv1 = *(const uint4*)&Kb[kvrow + (size_t)(r0 + 32) * 64 + c0];
  uint4 vv0 = *(const uint4*)&Vt[kvrow + (size_t)r0 * 2048 + c0];
  uint4 vv1 = *(const uint4*)&Vt[kvrow + (size_t)(r0 + 32) * 2048 + c0];
  f32x4 biasf[4];
#pragma unroll
  for (int fr = 0; fr < 4; ++fr)
    biasf[fr] = *(const f32x4*)&pbp[fr * 16];

  for (int kt = 0; kt <= qt; ++kt) {
    const int k0 = kt * 64;
    __syncthreads();  // previous tile's LDS reads complete
    *(uint4*)&sK[r0][c0] = kv0;
    *(uint4*)&sK[r0 + 32][c0] = kv1;
    *(uint4*)&sV[r0][c0] = vv0;
    *(uint4*)&sV[r0 + 32][c0] = vv1;
    __syncthreads();
    // prefetch next tile's K/V (after the barrier so its vmcnt(0) drain
    // doesn't serialize them; they overlap the whole compute phase below)
    if (kt < qt) {
      const size_t nk = (size_t)(k0 + 64);
      kv0 = *(const uint4*)&Kb[kvrow + nk * 64 + (size_t)r0 * 64 + c0];
      kv1 = *(const uint4*)&Kb[kvrow + nk * 64 + (size_t)(r0 + 32) * 64 + c0];
      vv0 = *(const uint4*)&Vt[kvrow + nk + (size_t)r0 * 2048 + c0];
      vv1 = *(const uint4*)&Vt[kvrow + nk + (size_t)(r0 + 32) * 2048 + c0];
    }

    // S^T = K Q^T (Q pre-scaled by scale*log2e). Lane holds S[qrow][key]
    // for key = k0 + fr*16 + kloc + r.
    f32x4 s[4];
#pragma unroll
    for (int fr = 0; fr < 4; ++fr) {
      bf16x8 kb0 = *(const bf16x8*)&sK[fr * 16 + t16][quad * 8];
      bf16x8 kb1 = *(const bf16x8*)&sK[fr * 16 + t16][32 + quad * 8];
      f32x4 z = (f32x4){0.f, 0.f, 0.f, 0.f};
      z = MFMA16(kb0, qa0, z);
      z = MFMA16(kb1, qa1, z);
      s[fr] = z;
    }
    // + pos_bias*log2e (fma)
#pragma unroll
    for (int fr = 0; fr < 4; ++fr)
#pragma unroll
      for (int r = 0; r < 4; ++r)
        s[fr][r] = fmaf(biasf[fr][r], LOG2E, s[fr][r]);
    // causal mask: only the diagonal tile has masked entries
    if (kt == qt) {
#pragma unroll
      for (int fr = 0; fr < 4; ++fr)
#pragma unroll
        for (int r = 0; r < 4; ++r)
          if (k0 + fr * 16 + kloc + r > qrow) s[fr][r] = -1e30f;
    }
    // prefetch next tile's bias into regs (overlaps softmax + PV below)
    if (kt < qt) {
#pragma unroll
      for (int fr = 0; fr < 4; ++fr)
        biasf[fr] = *(const f32x4*)&pbp[k0 + 64 + fr * 16];
    }

    // row max: in-lane tree over 16, then combine the 4 quad-siblings
    float mxa = fmaxf(fmaxf(s[0][0], s[0][1]), fmaxf(s[0][2], s[0][3]));
    float mxb = fmaxf(fmaxf(s[1][0], s[1][1]), fmaxf(s[1][2], s[1][3]));
    float mxc = fmaxf(fmaxf(s[2][0], s[2][1]), fmaxf(s[2][2], s[2][3]));
    float mxd = fmaxf(fmaxf(s[3][0], s[3][1]), fmaxf(s[3][2], s[3][3]));
    float mx = fmaxf(fmaxf(mxa, mxb), fmaxf(mxc, mxd));
    mx = fmaxf(mx, __shfl_xor(mx, 16));
    mx = fmaxf(mx, __shfl_xor(mx, 32));

    // online softmax (log2 domain); exact skip when no row max grows
    float al = 1.f;
    const bool grow = __any(mx > m) != 0;  // wave-uniform
    if (grow) {
      const float mn = fmaxf(m, mx);
      al = exp2f(m - mn);
      m = mn;
    }
    float rsa = 0.f, rsb = 0.f;
#pragma unroll
    for (int fr = 0; fr < 4; ++fr) {
      float p0 = exp2f(s[fr][0] - m);
      float p1 = exp2f(s[fr][1] - m);
      float p2 = exp2f(s[fr][2] - m);
      float p3 = exp2f(s[fr][3] - m);
      s[fr][0] = p0; s[fr][1] = p1; s[fr][2] = p2; s[fr][3] = p3;
      rsa += p0 + p1;
      rsb += p2 + p3;
    }
    float rs = rsa + rsb;
    rs += __shfl_xor(rs, 16);
    rs += __shfl_xor(rs, 32);
    l = fmaf(l, al, rs);
    // rescale accO: need al of rows quad*4+r (held by lanes t16==quad*4+r)
    if (grow) {
#pragma unroll
      for (int r = 0; r < 4; ++r) {
        const float alr = __shfl(al, (lane & 48) + kloc + r);
        accO[0][r] *= alr;
        accO[1][r] *= alr;
        accO[2][r] *= alr;
        accO[3][r] *= alr;
      }
    }

    // P: lane-row layout -> A-layout via per-wave LDS slice (no barrier:
    // same-wave DS ops are in-order; compiler inserts the lgkmcnt wait).
    // Lane's 4 keys per fr are consecutive -> one packed 8B write each.
#pragma unroll
    for (int fr = 0; fr < 4; ++fr) {
      uint2 pv;
      pv.x = pk2(s[fr][0], s[fr][1]);
      pv.y = pk2(s[fr][2], s[fr][3]);
      *(uint2*)&sQP[wave * 16 + t16][fr * 16 + kloc] = pv;
    }
    const bf16x8 pa0 = *(const bf16x8*)&sQP[wave * 16 + t16][quad * 8];
    const bf16x8 pa1 = *(const bf16x8*)&sQP[wave * 16 + t16][32 + quad * 8];
#pragma unroll
    for (int fc = 0; fc < 4; ++fc) {
      bf16x8 vb0 = *(const bf16x8*)&sV[fc * 16 + t16][quad * 8];
      bf16x8 vb1 = *(const bf16x8*)&sV[fc * 16 + t16][32 + quad * 8];
      accO[fc] = MFMA16(pa0, vb0, accO[fc]);
      accO[fc] = MFMA16(pa1, vb1, accO[fc]);
    }
  }

  // epilogue: 1/l lives per-lane (row t16); broadcast to accO rows quad*4+r
  const float inv = 1.f / l;
  float invr[4];
#pragma unroll
  for (int r = 0; r < 4; ++r) invr[r] = __shfl(inv, (lane & 48) + kloc + r);
  const size_t obase = (size_t)b * 2048 * 1024 + (size_t)h * 64;
#pragma unroll
  for (int fc = 0; fc < 4; ++fc)
#pragma unroll
    for (int r = 0; r < 4; ++r)
      Ao[obase + (size_t)(q0 + wave * 16 + quad * 4 + r) * 1024 + fc * 16 +
         t16] = f2b(accO[fc][r] * invr[r]);
}

extern "C" void kernel_launch(void* const* d_in, const int* in_sizes, int n_in,
                              void* d_out, int out_size, void* d_ws,
                              size_t ws_size, hipStream_t stream) {
  (void)in_sizes;
  (void)n_in;
  (void)out_size;
  (void)ws_size;
  const float* x = (const float*)d_in[0];
  const float* pb = (const float*)d_in[1];
  const float* wqkv = (const float*)d_in[2];
  const float* wpro = (const float*)d_in[3];
  const float* bpro = (const float*)d_in[4];

  unsigned short* ws = (unsigned short*)d_ws;
  unsigned short* wqkvT = ws;                   // 3072*1024 bf16
  unsigned short* wproT = wqkvT + 3072 * 1024;  // 1024*1024 bf16
  unsigned short* Qb = wproT + 1024 * 1024;     // [4,16,2048,64] bf16
  unsigned short* Kb = Qb + 8388608;            // [4,16,2048,64] bf16
  unsigned short* Vtb = Kb + 8388608;           // [4,16,64,2048] bf16
  unsigned short* Ao = Vtb + 8388608;           // [8192,1024] bf16
  unsigned short* xb = Ao;  // x-bf16 alias: dead before attn writes Ao

  conv_f32_bf16<<<4096, 256, 0, stream>>>(x, xb);
  transpose_f32_bf16<<<dim3(48, 16), 256, 0, stream>>>(wqkv, wqkvT, 1024, 3072);
  transpose_f32_bf16<<<dim3(16, 16), 256, 0, stream>>>(wpro, wproT, 1024, 1024);
  gemm_bt<0><<<dim3(24, 64), 256, 0, stream>>>(xb, wqkvT, Qb, Kb, Vtb, nullptr,
                                               nullptr, 1024, 3072);
  attn_kernel<<<2048, 256, 0, stream>>>(Qb, Kb, Vtb, pb, Ao);
  gemm_bt<1><<<dim3(8, 64), 256, 0, stream>>>(Ao, wproT, nullptr, nullptr,
                                              nullptr, (float*)d_out, bpro,
                                              1024, 1024);
}

// Round 2
// 581.625 us; speedup vs baseline: 1.0088x; 1.0088x over previous
//
#include <hip/hip_runtime.h>
#include <hip/hip_bf16.h>
#include <math.h>

typedef __attribute__((ext_vector_type(8))) short bf16x8;
typedef __attribute__((ext_vector_type(4))) float f32x4;
typedef __attribute__((ext_vector_type(8))) unsigned short u16x8;

#define MFMA16(a, b, c) __builtin_amdgcn_mfma_f32_16x16x32_bf16(a, b, c, 0, 0, 0)
#define LOG2E 1.4426950408889634f

__device__ __forceinline__ unsigned short f2b(float f) {
  __hip_bfloat16 h = __float2bfloat16(f);
  return *reinterpret_cast<unsigned short*>(&h);
}

__device__ __forceinline__ unsigned int pk2(float lo, float hi) {
  return (unsigned int)f2b(lo) | ((unsigned int)f2b(hi) << 16);
}

// async global->LDS, 16B per lane; lds base must be wave-uniform
__device__ __forceinline__ void gload16(const unsigned short* g,
                                        unsigned short* lds) {
  __builtin_amdgcn_global_load_lds(
      (const __attribute__((address_space(1))) unsigned int*)g,
      (__attribute__((address_space(3))) unsigned int*)lds, 16, 0, 0);
}

// load 8 fp32, return 8 bf16 packed in a uint4
__device__ __forceinline__ uint4 cvt8(const float* __restrict__ p) {
  float4 a = *(const float4*)p;
  float4 b = *(const float4*)(p + 4);
  union {
    unsigned short us[8];
    uint4 u;
  } r;
  r.us[0] = f2b(a.x); r.us[1] = f2b(a.y); r.us[2] = f2b(a.z); r.us[3] = f2b(a.w);
  r.us[4] = f2b(b.x); r.us[5] = f2b(b.y); r.us[6] = f2b(b.z); r.us[7] = f2b(b.w);
  return r.u;
}

// flat fp32 -> bf16 convert, 8 elems/thread
__global__ __launch_bounds__(256) void conv_f32_bf16(
    const float* __restrict__ in, unsigned short* __restrict__ out) {
  size_t i = ((size_t)blockIdx.x * 256 + threadIdx.x) * 8;
  *(uint4*)&out[i] = cvt8(in + i);
}

// out_bf16[c][r] = bf16(in_f32[r][c]); R, C multiples of 64
__global__ __launch_bounds__(256) void transpose_f32_bf16(
    const float* __restrict__ in, unsigned short* __restrict__ out, int R,
    int C) {
  __shared__ unsigned short tile[64][72];
  const int tR = blockIdx.y * 64, tC = blockIdx.x * 64;
  const int t = threadIdx.x;
#pragma unroll
  for (int p = 0; p < 4; ++p) {
    int u = t + p * 256, r = u >> 4, c = (u & 15) * 4;
    float4 v = *(const float4*)&in[(size_t)(tR + r) * C + tC + c];
    tile[r][c] = f2b(v.x);
    tile[r][c + 1] = f2b(v.y);
    tile[r][c + 2] = f2b(v.z);
    tile[r][c + 3] = f2b(v.w);
  }
  __syncthreads();
#pragma unroll
  for (int p = 0; p < 2; ++p) {
    int u = t + p * 256, orow = u >> 3, oc = (u & 7) * 8;
    u16x8 v;
#pragma unroll
    for (int e = 0; e < 8; ++e) v[e] = tile[oc + e][orow];
    *(u16x8*)&out[(size_t)(tC + orow) * R + tR + oc] = v;
  }
}

// C[M][N] = A[M][K] * Bt[N][K]^T, 128x128 tile, 4 waves, 16x16x32 MFMA.
// m97 structure: linear LDS tiles + global_load_lds width-16 staging,
// 2-barrier K-loop. A is bf16. MODE 0: epilogue splits into Q*scale / K /
// V^T head layouts. MODE 1: epilogue adds fp32 bias, stores fp32 row-major.
template <int MODE>
__global__ __launch_bounds__(256, 3) void gemm_bt(
    const unsigned short* __restrict__ A, const unsigned short* __restrict__ Bt,
    unsigned short* __restrict__ O0, unsigned short* __restrict__ O1,
    unsigned short* __restrict__ O2, float* __restrict__ OF,
    const float* __restrict__ bias, int K, int N) {
  __shared__ unsigned short sA[128][32];  // linear: required by gload_lds
  __shared__ unsigned short sB[128][32];
  const int m0 = blockIdx.y * 128, n0 = blockIdx.x * 128;
  const int t = threadIdx.x;
  const int wave = t >> 6, lane = t & 63, quad = lane >> 4, t16 = lane & 15;
  const int wr = (wave >> 1) * 64, wc = (wave & 1) * 64;

  f32x4 acc[4][4];
#pragma unroll
  for (int i = 0; i < 4; ++i)
#pragma unroll
    for (int j = 0; j < 4; ++j) acc[i][j] = (f32x4){0.f, 0.f, 0.f, 0.f};

  // staging: wave w stages 16-row chunks w and w+4 of each tile.
  // lane l covers row 16c + l/4, col elems (l&3)*8 (16B), matching the
  // hardware dest rule: wave-uniform LDS base + lane*16.
  const int srow = wave * 16 + (lane >> 2);
  const int scol = (lane & 3) * 8;
  const unsigned short* Ap0 = A + (size_t)(m0 + srow) * K + scol;
  const unsigned short* Ap1 = A + (size_t)(m0 + srow + 64) * K + scol;
  const unsigned short* Bp0 = Bt + (size_t)(n0 + srow) * K + scol;
  const unsigned short* Bp1 = Bt + (size_t)(n0 + srow + 64) * K + scol;
  unsigned short* ldsA0 = &sA[wave * 16][0];
  unsigned short* ldsA1 = &sA[wave * 16 + 64][0];
  unsigned short* ldsB0 = &sB[wave * 16][0];
  unsigned short* ldsB1 = &sB[wave * 16 + 64][0];

  for (int k0 = 0; k0 < K; k0 += 32) {
    __syncthreads();  // previous tile's LDS reads complete
    gload16(Ap0 + k0, ldsA0);
    gload16(Ap1 + k0, ldsA1);
    gload16(Bp0 + k0, ldsB0);
    gload16(Bp1 + k0, ldsB1);
    __syncthreads();  // drains vmcnt -> tile visible
    bf16x8 af[4], bf[4];
#pragma unroll
    for (int i = 0; i < 4; ++i)
      af[i] = *(const bf16x8*)&sA[wr + i * 16 + t16][quad * 8];
#pragma unroll
    for (int j = 0; j < 4; ++j)
      bf[j] = *(const bf16x8*)&sB[wc + j * 16 + t16][quad * 8];
#pragma unroll
    for (int i = 0; i < 4; ++i)
#pragma unroll
      for (int j = 0; j < 4; ++j) acc[i][j] = MFMA16(af[i], bf[j], acc[i][j]);
  }

#pragma unroll
  for (int i = 0; i < 4; ++i) {
    const int mrow = m0 + wr + i * 16 + quad * 4;  // + r
#pragma unroll
    for (int j = 0; j < 4; ++j) {
      const int ncol = n0 + wc + j * 16 + t16;
#pragma unroll
      for (int r = 0; r < 4; ++r) {
        const float v = acc[i][j][r];
        const int mr = mrow + r;
        if (MODE == 0) {
          const int bb = mr >> 11, nn = mr & 2047;
          const int sec = ncol >> 10, rem = ncol & 1023;
          const int hh = rem >> 6, dd = rem & 63;
          const size_t bhh = (size_t)bb * 16 + hh;
          if (sec == 0)  // Q * (scale*log2e): softmax runs in log2 domain
            O0[(bhh * 2048 + nn) * 64 + dd] = f2b(v * (0.125f * LOG2E));
          else if (sec == 1)
            O1[(bhh * 2048 + nn) * 64 + dd] = f2b(v);  // K
          else
            O2[(bhh * 64 + dd) * 2048 + nn] = f2b(v);  // V^T
        } else {
          OF[(size_t)mr * N + ncol] = v + bias[ncol];
        }
      }
    }
  }
}

// Flash attention: block = (b,h, 64-row q tile), 4 waves of 16 q rows each.
// qt-major-descending dispatch order; K/V reg-prefetch pipeline; softmax in
// log2 domain. Swapped-operand QK^T (S^T = K*Q^T): each lane owns one full
// q-row of S (16 keys in-lane, x4 quad-siblings) so row max/sum are in-lane
// trees + 2 cross-quad shuffles; bias loads are float4; causal mask only on
// the diagonal tile; P repack via 4x ds_write_b64; rescale skipped when no
// row max grows.
__global__ __launch_bounds__(256, 4) void attn_kernel(
    const unsigned short* __restrict__ Q, const unsigned short* __restrict__ Kb,
    const unsigned short* __restrict__ Vt, const float* __restrict__ PB,
    unsigned short* __restrict__ Ao) {
  __shared__ unsigned short sK[64][72];
  __shared__ unsigned short sV[64][72];   // sV[d][key]
  __shared__ unsigned short sQP[64][72];  // Q staging, then per-wave P buffer

  const int bh = blockIdx.x & 63;
  const int qt = 31 - (blockIdx.x >> 6);  // heavy q-tiles dispatch first
  const int h = bh & 15;
  const int b = bh >> 4;
  const int q0 = qt * 64;
  const int t = threadIdx.x;
  const int wave = t >> 6, lane = t & 63, quad = lane >> 4, t16 = lane & 15;
  const int kloc = quad * 4;  // this lane's local key base within a 16-chunk

  const size_t qbase = ((size_t)bh * 2048 + q0) * 64;
#pragma unroll
  for (int p = 0; p < 2; ++p) {
    int u = t + p * 256, r = u >> 3, c = (u & 7) * 8;
    *(uint4*)&sQP[r][c] = *(const uint4*)&Q[qbase + r * 64 + c];
  }
  __syncthreads();
  const bf16x8 qa0 = *(const bf16x8*)&sQP[wave * 16 + t16][quad * 8];
  const bf16x8 qa1 = *(const bf16x8*)&sQP[wave * 16 + t16][32 + quad * 8];
  // sQP is reused as P buffer inside the loop; iteration-0's two barriers
  // order every wave's Q-frag reads before the first P write.

  f32x4 accO[4];
#pragma unroll
  for (int i = 0; i < 4; ++i) accO[i] = (f32x4){0.f, 0.f, 0.f, 0.f};
  float m = -INFINITY, l = 0.f;  // per-lane: stats for ONE q row

  const int qrow = q0 + wave * 16 + t16;  // this lane's q row
  const int r0 = t >> 3, c0 = (t & 7) * 8;
  const size_t kvrow = (size_t)bh * 2048 * 64;
  // bias for this lane's row: components r=0..3 are consecutive keys
  const float* pbp =
      PB + (size_t)h * 4194304 + (size_t)qrow * 2048 + kloc;

  // ---- prefetch tile 0 (K/V into regs, bias as float4) ----
  uint4 kv0 = *(const uint4*)&Kb[kvrow + (size_t)r0 * 64 + c0];
  uint4 kv1 = *(const uint4*)&Kb[kvrow + (size_t)(r0 + 32) * 64 + c0];
  uint4 vv0 = *(const uint4*)&Vt[kvrow + (size_t)r0 * 2048 + c0];
  uint4 vv1 = *(const uint4*)&Vt[kvrow + (size_t)(r0 + 32) * 2048 + c0];
  f32x4 biasf[4];
#pragma unroll
  for (int fr = 0; fr < 4; ++fr)
    biasf[fr] = *(const f32x4*)&pbp[fr * 16];

  for (int kt = 0; kt <= qt; ++kt) {
    const int k0 = kt * 64;
    __syncthreads();  // previous tile's LDS reads complete
    *(uint4*)&sK[r0][c0] = kv0;
    *(uint4*)&sK[r0 + 32][c0] = kv1;
    *(uint4*)&sV[r0][c0] = vv0;
    *(uint4*)&sV[r0 + 32][c0] = vv1;
    __syncthreads();
    // prefetch next tile's K/V (after the barrier so its vmcnt(0) drain
    // doesn't serialize them; they overlap the whole compute phase below)
    if (kt < qt) {
      const size_t nk = (size_t)(k0 + 64);
      kv0 = *(const uint4*)&Kb[kvrow + nk * 64 + (size_t)r0 * 64 + c0];
      kv1 = *(const uint4*)&Kb[kvrow + nk * 64 + (size_t)(r0 + 32) * 64 + c0];
      vv0 = *(const uint4*)&Vt[kvrow + nk + (size_t)r0 * 2048 + c0];
      vv1 = *(const uint4*)&Vt[kvrow + nk + (size_t)(r0 + 32) * 2048 + c0];
    }

    // S^T = K Q^T (Q pre-scaled by scale*log2e). Lane holds S[qrow][key]
    // for key = k0 + fr*16 + kloc + r.
    f32x4 s[4];
#pragma unroll
    for (int fr = 0; fr < 4; ++fr) {
      bf16x8 kb0 = *(const bf16x8*)&sK[fr * 16 + t16][quad * 8];
      bf16x8 kb1 = *(const bf16x8*)&sK[fr * 16 + t16][32 + quad * 8];
      f32x4 z = (f32x4){0.f, 0.f, 0.f, 0.f};
      z = MFMA16(kb0, qa0, z);
      z = MFMA16(kb1, qa1, z);
      s[fr] = z;
    }
    // + pos_bias*log2e (fma)
#pragma unroll
    for (int fr = 0; fr < 4; ++fr)
#pragma unroll
      for (int r = 0; r < 4; ++r)
        s[fr][r] = fmaf(biasf[fr][r], LOG2E, s[fr][r]);
    // causal mask: only the diagonal tile has masked entries
    if (kt == qt) {
#pragma unroll
      for (int fr = 0; fr < 4; ++fr)
#pragma unroll
        for (int r = 0; r < 4; ++r)
          if (k0 + fr * 16 + kloc + r > qrow) s[fr][r] = -1e30f;
    }
    // prefetch next tile's bias into regs (overlaps softmax + PV below)
    if (kt < qt) {
#pragma unroll
      for (int fr = 0; fr < 4; ++fr)
        biasf[fr] = *(const f32x4*)&pbp[k0 + 64 + fr * 16];
    }

    // row max: in-lane tree over 16, then combine the 4 quad-siblings
    float mxa = fmaxf(fmaxf(s[0][0], s[0][1]), fmaxf(s[0][2], s[0][3]));
    float mxb = fmaxf(fmaxf(s[1][0], s[1][1]), fmaxf(s[1][2], s[1][3]));
    float mxc = fmaxf(fmaxf(s[2][0], s[2][1]), fmaxf(s[2][2], s[2][3]));
    float mxd = fmaxf(fmaxf(s[3][0], s[3][1]), fmaxf(s[3][2], s[3][3]));
    float mx = fmaxf(fmaxf(mxa, mxb), fmaxf(mxc, mxd));
    mx = fmaxf(mx, __shfl_xor(mx, 16));
    mx = fmaxf(mx, __shfl_xor(mx, 32));

    // online softmax (log2 domain); exact skip when no row max grows
    float al = 1.f;
    const bool grow = __any(mx > m) != 0;  // wave-uniform
    if (grow) {
      const float mn = fmaxf(m, mx);
      al = exp2f(m - mn);
      m = mn;
    }
    float rsa = 0.f, rsb = 0.f;
#pragma unroll
    for (int fr = 0; fr < 4; ++fr) {
      float p0 = exp2f(s[fr][0] - m);
      float p1 = exp2f(s[fr][1] - m);
      float p2 = exp2f(s[fr][2] - m);
      float p3 = exp2f(s[fr][3] - m);
      s[fr][0] = p0; s[fr][1] = p1; s[fr][2] = p2; s[fr][3] = p3;
      rsa += p0 + p1;
      rsb += p2 + p3;
    }
    float rs = rsa + rsb;
    rs += __shfl_xor(rs, 16);
    rs += __shfl_xor(rs, 32);
    l = fmaf(l, al, rs);
    // rescale accO: need al of rows quad*4+r (held by lanes t16==quad*4+r)
    if (grow) {
#pragma unroll
      for (int r = 0; r < 4; ++r) {
        const float alr = __shfl(al, (lane & 48) + kloc + r);
        accO[0][r] *= alr;
        accO[1][r] *= alr;
        accO[2][r] *= alr;
        accO[3][r] *= alr;
      }
    }

    // P: lane-row layout -> A-layout via per-wave LDS slice (no barrier:
    // same-wave DS ops are in-order; compiler inserts the lgkmcnt wait).
    // Lane's 4 keys per fr are consecutive -> one packed 8B write each.
#pragma unroll
    for (int fr = 0; fr < 4; ++fr) {
      uint2 pv;
      pv.x = pk2(s[fr][0], s[fr][1]);
      pv.y = pk2(s[fr][2], s[fr][3]);
      *(uint2*)&sQP[wave * 16 + t16][fr * 16 + kloc] = pv;
    }
    const bf16x8 pa0 = *(const bf16x8*)&sQP[wave * 16 + t16][quad * 8];
    const bf16x8 pa1 = *(const bf16x8*)&sQP[wave * 16 + t16][32 + quad * 8];
#pragma unroll
    for (int fc = 0; fc < 4; ++fc) {
      bf16x8 vb0 = *(const bf16x8*)&sV[fc * 16 + t16][quad * 8];
      bf16x8 vb1 = *(const bf16x8*)&sV[fc * 16 + t16][32 + quad * 8];
      accO[fc] = MFMA16(pa0, vb0, accO[fc]);
      accO[fc] = MFMA16(pa1, vb1, accO[fc]);
    }
  }

  // epilogue: 1/l lives per-lane (row t16); broadcast to accO rows quad*4+r
  const float inv = 1.f / l;
  float invr[4];
#pragma unroll
  for (int r = 0; r < 4; ++r) invr[r] = __shfl(inv, (lane & 48) + kloc + r);
  const size_t obase = (size_t)b * 2048 * 1024 + (size_t)h * 64;
#pragma unroll
  for (int fc = 0; fc < 4; ++fc)
#pragma unroll
    for (int r = 0; r < 4; ++r)
      Ao[obase + (size_t)(q0 + wave * 16 + quad * 4 + r) * 1024 + fc * 16 +
         t16] = f2b(accO[fc][r] * invr[r]);
}

extern "C" void kernel_launch(void* const* d_in, const int* in_sizes, int n_in,
                              void* d_out, int out_size, void* d_ws,
                              size_t ws_size, hipStream_t stream) {
  (void)in_sizes;
  (void)n_in;
  (void)out_size;
  (void)ws_size;
  const float* x = (const float*)d_in[0];
  const float* pb = (const float*)d_in[1];
  const float* wqkv = (const float*)d_in[2];
  const float* wpro = (const float*)d_in[3];
  const float* bpro = (const float*)d_in[4];

  unsigned short* ws = (unsigned short*)d_ws;
  unsigned short* wqkvT = ws;                   // 3072*1024 bf16
  unsigned short* wproT = wqkvT + 3072 * 1024;  // 1024*1024 bf16
  unsigned short* Qb = wproT + 1024 * 1024;     // [4,16,2048,64] bf16
  unsigned short* Kb = Qb + 8388608;            // [4,16,2048,64] bf16
  unsigned short* Vtb = Kb + 8388608;           // [4,16,64,2048] bf16
  unsigned short* Ao = Vtb + 8388608;           // [8192,1024] bf16
  unsigned short* xb = Ao;  // x-bf16 alias: dead before attn writes Ao

  conv_f32_bf16<<<4096, 256, 0, stream>>>(x, xb);
  transpose_f32_bf16<<<dim3(48, 16), 256, 0, stream>>>(wqkv, wqkvT, 1024, 3072);
  transpose_f32_bf16<<<dim3(16, 16), 256, 0, stream>>>(wpro, wproT, 1024, 1024);
  gemm_bt<0><<<dim3(24, 64), 256, 0, stream>>>(xb, wqkvT, Qb, Kb, Vtb, nullptr,
                                               nullptr, 1024, 3072);
  attn_kernel<<<2048, 256, 0, stream>>>(Qb, Kb, Vtb, pb, Ao);
  gemm_bt<1><<<dim3(8, 64), 256, 0, stream>>>(Ao, wproT, nullptr, nullptr,
                                              nullptr, (float*)d_out, bpro,
                                              1024, 1024);
}

// Round 3
// 549.828 us; speedup vs baseline: 1.0671x; 1.0578x over previous
//
#include <hip/hip_runtime.h>
#include <hip/hip_bf16.h>
#include <math.h>

typedef __attribute__((ext_vector_type(8))) short bf16x8;
typedef __attribute__((ext_vector_type(4))) float f32x4;
typedef __attribute__((ext_vector_type(8))) unsigned short u16x8;

#define MFMA16(a, b, c) __builtin_amdgcn_mfma_f32_16x16x32_bf16(a, b, c, 0, 0, 0)
#define LOG2E 1.4426950408889634f

__device__ __forceinline__ unsigned short f2b(float f) {
  __hip_bfloat16 h = __float2bfloat16(f);
  return *reinterpret_cast<unsigned short*>(&h);
}

__device__ __forceinline__ unsigned int pk2(float lo, float hi) {
  return (unsigned int)f2b(lo) | ((unsigned int)f2b(hi) << 16);
}

// async global->LDS, 16B per lane; lds base must be wave-uniform
__device__ __forceinline__ void gload16(const unsigned short* g,
                                        unsigned short* lds) {
  __builtin_amdgcn_global_load_lds(
      (const __attribute__((address_space(1))) unsigned int*)g,
      (__attribute__((address_space(3))) unsigned int*)lds, 16, 0, 0);
}

// load 8 fp32, return 8 bf16 packed in a uint4
__device__ __forceinline__ uint4 cvt8(const float* __restrict__ p) {
  float4 a = *(const float4*)p;
  float4 b = *(const float4*)(p + 4);
  union {
    unsigned short us[8];
    uint4 u;
  } r;
  r.us[0] = f2b(a.x); r.us[1] = f2b(a.y); r.us[2] = f2b(a.z); r.us[3] = f2b(a.w);
  r.us[4] = f2b(b.x); r.us[5] = f2b(b.y); r.us[6] = f2b(b.z); r.us[7] = f2b(b.w);
  return r.u;
}

// flat fp32 -> bf16 convert, 8 elems/thread
__global__ __launch_bounds__(256) void conv_f32_bf16(
    const float* __restrict__ in, unsigned short* __restrict__ out) {
  size_t i = ((size_t)blockIdx.x * 256 + threadIdx.x) * 8;
  *(uint4*)&out[i] = cvt8(in + i);
}

// out_bf16[c][r] = bf16(in_f32[r][c]); R, C multiples of 64
__global__ __launch_bounds__(256) void transpose_f32_bf16(
    const float* __restrict__ in, unsigned short* __restrict__ out, int R,
    int C) {
  __shared__ unsigned short tile[64][72];
  const int tR = blockIdx.y * 64, tC = blockIdx.x * 64;
  const int t = threadIdx.x;
#pragma unroll
  for (int p = 0; p < 4; ++p) {
    int u = t + p * 256, r = u >> 4, c = (u & 15) * 4;
    float4 v = *(const float4*)&in[(size_t)(tR + r) * C + tC + c];
    tile[r][c] = f2b(v.x);
    tile[r][c + 1] = f2b(v.y);
    tile[r][c + 2] = f2b(v.z);
    tile[r][c + 3] = f2b(v.w);
  }
  __syncthreads();
#pragma unroll
  for (int p = 0; p < 2; ++p) {
    int u = t + p * 256, orow = u >> 3, oc = (u & 7) * 8;
    u16x8 v;
#pragma unroll
    for (int e = 0; e < 8; ++e) v[e] = tile[oc + e][orow];
    *(u16x8*)&out[(size_t)(tC + orow) * R + tR + oc] = v;
  }
}

// C[M][N] = A[M][K] * Bt[N][K]^T, 128x128 tile, 4 waves, 16x16x32 MFMA.
// m97 structure: linear LDS tiles + global_load_lds width-16 staging,
// 2-barrier K-loop. A is bf16.
// MODE 0: epilogue splits into Q*scale / K / V^T head layouts. The section
//   is block-uniform (N=3072, 128-wide tiles). V-blocks transpose their
//   C-tile through padded LDS so V^T stores are coalesced u16x8 along nn
//   (the naive path was 2B stores at 4KB stride: ~32x L2 write-transaction
//   amplification, store-bound).
// MODE 1: epilogue adds fp32 bias, stores fp32 row-major.
template <int MODE>
__global__ __launch_bounds__(256, 3) void gemm_bt(
    const unsigned short* __restrict__ A, const unsigned short* __restrict__ Bt,
    unsigned short* __restrict__ O0, unsigned short* __restrict__ O1,
    unsigned short* __restrict__ O2, float* __restrict__ OF,
    const float* __restrict__ bias, int K, int N) {
  __shared__ unsigned short sA[128][32];  // linear: required by gload_lds
  __shared__ unsigned short sB[128][32];
  const int m0 = blockIdx.y * 128, n0 = blockIdx.x * 128;
  const int t = threadIdx.x;
  const int wave = t >> 6, lane = t & 63, quad = lane >> 4, t16 = lane & 15;
  const int wr = (wave >> 1) * 64, wc = (wave & 1) * 64;

  f32x4 acc[4][4];
#pragma unroll
  for (int i = 0; i < 4; ++i)
#pragma unroll
    for (int j = 0; j < 4; ++j) acc[i][j] = (f32x4){0.f, 0.f, 0.f, 0.f};

  // staging: wave w stages 16-row chunks w and w+4 of each tile.
  // lane l covers row 16c + l/4, col elems (l&3)*8 (16B), matching the
  // hardware dest rule: wave-uniform LDS base + lane*16.
  const int srow = wave * 16 + (lane >> 2);
  const int scol = (lane & 3) * 8;
  const unsigned short* Ap0 = A + (size_t)(m0 + srow) * K + scol;
  const unsigned short* Ap1 = A + (size_t)(m0 + srow + 64) * K + scol;
  const unsigned short* Bp0 = Bt + (size_t)(n0 + srow) * K + scol;
  const unsigned short* Bp1 = Bt + (size_t)(n0 + srow + 64) * K + scol;
  unsigned short* ldsA0 = &sA[wave * 16][0];
  unsigned short* ldsA1 = &sA[wave * 16 + 64][0];
  unsigned short* ldsB0 = &sB[wave * 16][0];
  unsigned short* ldsB1 = &sB[wave * 16 + 64][0];

  for (int k0 = 0; k0 < K; k0 += 32) {
    __syncthreads();  // previous tile's LDS reads complete
    gload16(Ap0 + k0, ldsA0);
    gload16(Ap1 + k0, ldsA1);
    gload16(Bp0 + k0, ldsB0);
    gload16(Bp1 + k0, ldsB1);
    __syncthreads();  // drains vmcnt -> tile visible
    bf16x8 af[4], bf[4];
#pragma unroll
    for (int i = 0; i < 4; ++i)
      af[i] = *(const bf16x8*)&sA[wr + i * 16 + t16][quad * 8];
#pragma unroll
    for (int j = 0; j < 4; ++j)
      bf[j] = *(const bf16x8*)&sB[wc + j * 16 + t16][quad * 8];
#pragma unroll
    for (int i = 0; i < 4; ++i)
#pragma unroll
      for (int j = 0; j < 4; ++j) acc[i][j] = MFMA16(af[i], bf[j], acc[i][j]);
  }

  if constexpr (MODE == 0) {
    const int bb = m0 >> 11, nn0 = m0 & 2047;
    if (n0 >= 2048) {
      // ---- V block: LDS transpose, then coalesced V^T stores ----
      // pad 129: column-gather stride 8*258B -> bank stride 4 -> <=4-way
      __shared__ unsigned short tV[128][129];
#pragma unroll
      for (int i = 0; i < 4; ++i)
#pragma unroll
        for (int j = 0; j < 4; ++j)
#pragma unroll
          for (int r = 0; r < 4; ++r)
            tV[wr + i * 16 + quad * 4 + r][wc + j * 16 + t16] =
                f2b(acc[i][j][r]);
      __syncthreads();
#pragma unroll
      for (int p = 0; p < 8; ++p) {
        const int u = t + p * 256;
        const int c = u >> 4;        // block-local output row (= tile col)
        const int g = (u & 15) * 8;  // m-chunk of 8
        u16x8 v;
#pragma unroll
        for (int e = 0; e < 8; ++e) v[e] = tV[g + e][c];
        const int rem = (n0 + c) & 1023;
        const int hh = rem >> 6, dd = rem & 63;
        const size_t bhh = (size_t)bb * 16 + hh;
        *(u16x8*)&O2[(bhh * 64 + dd) * 2048 + nn0 + g] = v;
      }
    } else {
      // ---- Q / K block: register epilogue (stores already coalesce) ----
      const int sec = n0 >> 10;  // 0 = Q, 1 = K (block-uniform)
#pragma unroll
      for (int i = 0; i < 4; ++i) {
        const int mrow = m0 + wr + i * 16 + quad * 4;  // + r
#pragma unroll
        for (int j = 0; j < 4; ++j) {
          const int ncol = n0 + wc + j * 16 + t16;
          const int rem = ncol & 1023;
          const int hh = rem >> 6, dd = rem & 63;
          const size_t bhh = (size_t)bb * 16 + hh;
#pragma unroll
          for (int r = 0; r < 4; ++r) {
            const int nn = (mrow + r) & 2047;
            if (sec == 0)  // Q * (scale*log2e): softmax in log2 domain
              O0[(bhh * 2048 + nn) * 64 + dd] =
                  f2b(acc[i][j][r] * (0.125f * LOG2E));
            else
              O1[(bhh * 2048 + nn) * 64 + dd] = f2b(acc[i][j][r]);  // K
          }
        }
      }
    }
  } else {
#pragma unroll
    for (int i = 0; i < 4; ++i) {
      const int mrow = m0 + wr + i * 16 + quad * 4;  // + r
#pragma unroll
      for (int j = 0; j < 4; ++j) {
        const int ncol = n0 + wc + j * 16 + t16;
#pragma unroll
        for (int r = 0; r < 4; ++r)
          OF[(size_t)(mrow + r) * N + ncol] = acc[i][j][r] + bias[ncol];
      }
    }
  }
}

// Flash attention: block = (b,h, 64-row q tile), 4 waves of 16 q rows each.
// qt-major-descending dispatch order; K/V reg-prefetch pipeline; softmax in
// log2 domain. Swapped-operand QK^T (S^T = K*Q^T): each lane owns one full
// q-row of S (16 keys in-lane, x4 quad-siblings) so row max/sum are in-lane
// trees + 2 cross-quad shuffles; bias loads are float4; causal mask only on
// the diagonal tile; P repack via 4x ds_write_b64; rescale skipped when no
// row max grows.
__global__ __launch_bounds__(256, 4) void attn_kernel(
    const unsigned short* __restrict__ Q, const unsigned short* __restrict__ Kb,
    const unsigned short* __restrict__ Vt, const float* __restrict__ PB,
    unsigned short* __restrict__ Ao) {
  __shared__ unsigned short sK[64][72];
  __shared__ unsigned short sV[64][72];   // sV[d][key]
  __shared__ unsigned short sQP[64][72];  // Q staging, then per-wave P buffer

  const int bh = blockIdx.x & 63;
  const int qt = 31 - (blockIdx.x >> 6);  // heavy q-tiles dispatch first
  const int h = bh & 15;
  const int b = bh >> 4;
  const int q0 = qt * 64;
  const int t = threadIdx.x;
  const int wave = t >> 6, lane = t & 63, quad = lane >> 4, t16 = lane & 15;
  const int kloc = quad * 4;  // this lane's local key base within a 16-chunk

  const size_t qbase = ((size_t)bh * 2048 + q0) * 64;
#pragma unroll
  for (int p = 0; p < 2; ++p) {
    int u = t + p * 256, r = u >> 3, c = (u & 7) * 8;
    *(uint4*)&sQP[r][c] = *(const uint4*)&Q[qbase + r * 64 + c];
  }
  __syncthreads();
  const bf16x8 qa0 = *(const bf16x8*)&sQP[wave * 16 + t16][quad * 8];
  const bf16x8 qa1 = *(const bf16x8*)&sQP[wave * 16 + t16][32 + quad * 8];
  // sQP is reused as P buffer inside the loop; iteration-0's two barriers
  // order every wave's Q-frag reads before the first P write.

  f32x4 accO[4];
#pragma unroll
  for (int i = 0; i < 4; ++i) accO[i] = (f32x4){0.f, 0.f, 0.f, 0.f};
  float m = -INFINITY, l = 0.f;  // per-lane: stats for ONE q row

  const int qrow = q0 + wave * 16 + t16;  // this lane's q row
  const int r0 = t >> 3, c0 = (t & 7) * 8;
  const size_t kvrow = (size_t)bh * 2048 * 64;
  // bias for this lane's row: components r=0..3 are consecutive keys
  const float* pbp =
      PB + (size_t)h * 4194304 + (size_t)qrow * 2048 + kloc;

  // ---- prefetch tile 0 (K/V into regs, bias as float4) ----
  uint4 kv0 = *(const uint4*)&Kb[kvrow + (size_t)r0 * 64 + c0];
  uint4 kv1 = *(const uint4*)&Kb[kvrow + (size_t)(r0 + 32) * 64 + c0];
  uint4 vv0 = *(const uint4*)&Vt[kvrow + (size_t)r0 * 2048 + c0];
  uint4 vv1 = *(const uint4*)&Vt[kvrow + (size_t)(r0 + 32) * 2048 + c0];
  f32x4 biasf[4];
#pragma unroll
  for (int fr = 0; fr < 4; ++fr)
    biasf[fr] = *(const f32x4*)&pbp[fr * 16];

  for (int kt = 0; kt <= qt; ++kt) {
    const int k0 = kt * 64;
    __syncthreads();  // previous tile's LDS reads complete
    *(uint4*)&sK[r0][c0] = kv0;
    *(uint4*)&sK[r0 + 32][c0] = kv1;
    *(uint4*)&sV[r0][c0] = vv0;
    *(uint4*)&sV[r0 + 32][c0] = vv1;
    __syncthreads();
    // prefetch next tile's K/V (after the barrier so its vmcnt(0) drain
    // doesn't serialize them; they overlap the whole compute phase below)
    if (kt < qt) {
      const size_t nk = (size_t)(k0 + 64);
      kv0 = *(const uint4*)&Kb[kvrow + nk * 64 + (size_t)r0 * 64 + c0];
      kv1 = *(const uint4*)&Kb[kvrow + nk * 64 + (size_t)(r0 + 32) * 64 + c0];
      vv0 = *(const uint4*)&Vt[kvrow + nk + (size_t)r0 * 2048 + c0];
      vv1 = *(const uint4*)&Vt[kvrow + nk + (size_t)(r0 + 32) * 2048 + c0];
    }

    // S^T = K Q^T (Q pre-scaled by scale*log2e). Lane holds S[qrow][key]
    // for key = k0 + fr*16 + kloc + r.
    f32x4 s[4];
#pragma unroll
    for (int fr = 0; fr < 4; ++fr) {
      bf16x8 kb0 = *(const bf16x8*)&sK[fr * 16 + t16][quad * 8];
      bf16x8 kb1 = *(const bf16x8*)&sK[fr * 16 + t16][32 + quad * 8];
      f32x4 z = (f32x4){0.f, 0.f, 0.f, 0.f};
      z = MFMA16(kb0, qa0, z);
      z = MFMA16(kb1, qa1, z);
      s[fr] = z;
    }
    // + pos_bias*log2e (fma)
#pragma unroll
    for (int fr = 0; fr < 4; ++fr)
#pragma unroll
      for (int r = 0; r < 4; ++r)
        s[fr][r] = fmaf(biasf[fr][r], LOG2E, s[fr][r]);
    // causal mask: only the diagonal tile has masked entries
    if (kt == qt) {
#pragma unroll
      for (int fr = 0; fr < 4; ++fr)
#pragma unroll
        for (int r = 0; r < 4; ++r)
          if (k0 + fr * 16 + kloc + r > qrow) s[fr][r] = -1e30f;
    }
    // prefetch next tile's bias into regs (overlaps softmax + PV below)
    if (kt < qt) {
#pragma unroll
      for (int fr = 0; fr < 4; ++fr)
        biasf[fr] = *(const f32x4*)&pbp[k0 + 64 + fr * 16];
    }

    // row max: in-lane tree over 16, then combine the 4 quad-siblings
    float mxa = fmaxf(fmaxf(s[0][0], s[0][1]), fmaxf(s[0][2], s[0][3]));
    float mxb = fmaxf(fmaxf(s[1][0], s[1][1]), fmaxf(s[1][2], s[1][3]));
    float mxc = fmaxf(fmaxf(s[2][0], s[2][1]), fmaxf(s[2][2], s[2][3]));
    float mxd = fmaxf(fmaxf(s[3][0], s[3][1]), fmaxf(s[3][2], s[3][3]));
    float mx = fmaxf(fmaxf(mxa, mxb), fmaxf(mxc, mxd));
    mx = fmaxf(mx, __shfl_xor(mx, 16));
    mx = fmaxf(mx, __shfl_xor(mx, 32));

    // online softmax (log2 domain); exact skip when no row max grows
    float al = 1.f;
    const bool grow = __any(mx > m) != 0;  // wave-uniform
    if (grow) {
      const float mn = fmaxf(m, mx);
      al = exp2f(m - mn);
      m = mn;
    }
    float rsa = 0.f, rsb = 0.f;
#pragma unroll
    for (int fr = 0; fr < 4; ++fr) {
      float p0 = exp2f(s[fr][0] - m);
      float p1 = exp2f(s[fr][1] - m);
      float p2 = exp2f(s[fr][2] - m);
      float p3 = exp2f(s[fr][3] - m);
      s[fr][0] = p0; s[fr][1] = p1; s[fr][2] = p2; s[fr][3] = p3;
      rsa += p0 + p1;
      rsb += p2 + p3;
    }
    float rs = rsa + rsb;
    rs += __shfl_xor(rs, 16);
    rs += __shfl_xor(rs, 32);
    l = fmaf(l, al, rs);
    // rescale accO: need al of rows quad*4+r (held by lanes t16==quad*4+r)
    if (grow) {
#pragma unroll
      for (int r = 0; r < 4; ++r) {
        const float alr = __shfl(al, (lane & 48) + kloc + r);
        accO[0][r] *= alr;
        accO[1][r] *= alr;
        accO[2][r] *= alr;
        accO[3][r] *= alr;
      }
    }

    // P: lane-row layout -> A-layout via per-wave LDS slice (no barrier:
    // same-wave DS ops are in-order; compiler inserts the lgkmcnt wait).
    // Lane's 4 keys per fr are consecutive -> one packed 8B write each.
#pragma unroll
    for (int fr = 0; fr < 4; ++fr) {
      uint2 pv;
      pv.x = pk2(s[fr][0], s[fr][1]);
      pv.y = pk2(s[fr][2], s[fr][3]);
      *(uint2*)&sQP[wave * 16 + t16][fr * 16 + kloc] = pv;
    }
    const bf16x8 pa0 = *(const bf16x8*)&sQP[wave * 16 + t16][quad * 8];
    const bf16x8 pa1 = *(const bf16x8*)&sQP[wave * 16 + t16][32 + quad * 8];
#pragma unroll
    for (int fc = 0; fc < 4; ++fc) {
      bf16x8 vb0 = *(const bf16x8*)&sV[fc * 16 + t16][quad * 8];
      bf16x8 vb1 = *(const bf16x8*)&sV[fc * 16 + t16][32 + quad * 8];
      accO[fc] = MFMA16(pa0, vb0, accO[fc]);
      accO[fc] = MFMA16(pa1, vb1, accO[fc]);
    }
  }

  // epilogue: 1/l lives per-lane (row t16); broadcast to accO rows quad*4+r
  const float inv = 1.f / l;
  float invr[4];
#pragma unroll
  for (int r = 0; r < 4; ++r) invr[r] = __shfl(inv, (lane & 48) + kloc + r);
  const size_t obase = (size_t)b * 2048 * 1024 + (size_t)h * 64;
#pragma unroll
  for (int fc = 0; fc < 4; ++fc)
#pragma unroll
    for (int r = 0; r < 4; ++r)
      Ao[obase + (size_t)(q0 + wave * 16 + quad * 4 + r) * 1024 + fc * 16 +
         t16] = f2b(accO[fc][r] * invr[r]);
}

extern "C" void kernel_launch(void* const* d_in, const int* in_sizes, int n_in,
                              void* d_out, int out_size, void* d_ws,
                              size_t ws_size, hipStream_t stream) {
  (void)in_sizes;
  (void)n_in;
  (void)out_size;
  (void)ws_size;
  const float* x = (const float*)d_in[0];
  const float* pb = (const float*)d_in[1];
  const float* wqkv = (const float*)d_in[2];
  const float* wpro = (const float*)d_in[3];
  const float* bpro = (const float*)d_in[4];

  unsigned short* ws = (unsigned short*)d_ws;
  unsigned short* wqkvT = ws;                   // 3072*1024 bf16
  unsigned short* wproT = wqkvT + 3072 * 1024;  // 1024*1024 bf16
  unsigned short* Qb = wproT + 1024 * 1024;     // [4,16,2048,64] bf16
  unsigned short* Kb = Qb + 8388608;            // [4,16,2048,64] bf16
  unsigned short* Vtb = Kb + 8388608;           // [4,16,64,2048] bf16
  unsigned short* Ao = Vtb + 8388608;           // [8192,1024] bf16
  unsigned short* xb = Ao;  // x-bf16 alias: dead before attn writes Ao

  conv_f32_bf16<<<4096, 256, 0, stream>>>(x, xb);
  transpose_f32_bf16<<<dim3(48, 16), 256, 0, stream>>>(wqkv, wqkvT, 1024, 3072);
  transpose_f32_bf16<<<dim3(16, 16), 256, 0, stream>>>(wpro, wproT, 1024, 1024);
  gemm_bt<0><<<dim3(24, 64), 256, 0, stream>>>(xb, wqkvT, Qb, Kb, Vtb, nullptr,
                                               nullptr, 1024, 3072);
  attn_kernel<<<2048, 256, 0, stream>>>(Qb, Kb, Vtb, pb, Ao);
  gemm_bt<1><<<dim3(8, 64), 256, 0, stream>>>(Ao, wproT, nullptr, nullptr,
                                              nullptr, (float*)d_out, bpro,
                                              1024, 1024);
}